// Round 15
// baseline (272.395 us; speedup 1.0000x reference)
//
#include <hip/hip_runtime.h>
#include <math.h>

#define NEG_INF (-__builtin_inff())

typedef __attribute__((ext_vector_type(8))) short short8;
typedef __attribute__((ext_vector_type(4))) float f32x4;

__device__ __forceinline__ unsigned f2bf(float f) {   // fp32 -> bf16 bits (RNE)
    union { float f; unsigned u; } v; v.f = f;
    return (v.u + 0x7fffu + ((v.u >> 16) & 1u)) >> 16;
}

// DPP row shifts within 16-lane rows. row_shr:n (0x110|n): lane i reads lane
// i-n within its 16-lane row; bound_ctrl=true -> out-of-row reads 0.
__device__ __forceinline__ float dpp_shr1(float x) {
    return __int_as_float(__builtin_amdgcn_update_dpp(
        0, __float_as_int(x), 0x111, 0xF, 0xF, true));
}
__device__ __forceinline__ float dpp_shr2(float x) {
    return __int_as_float(__builtin_amdgcn_update_dpp(
        0, __float_as_int(x), 0x112, 0xF, 0xF, true));
}
__device__ __forceinline__ float dpp_shr4(float x) {
    return __int_as_float(__builtin_amdgcn_update_dpp(
        0, __float_as_int(x), 0x114, 0xF, 0xF, true));
}
__device__ __forceinline__ float dpp_shr8(float x) {
    return __int_as_float(__builtin_amdgcn_update_dpp(
        0, __float_as_int(x), 0x118, 0xF, 0xF, true));
}
__device__ __forceinline__ float dpp_shl1(float x) {
    return __int_as_float(__builtin_amdgcn_update_dpp(
        0, __float_as_int(x), 0x101, 0xF, 0xF, true));
}

// ============ pad kernel: x channel -> zero-padded (4,66,66,66) bf16 ============
// Padded cell (z,y,x) = volume voxel (z-1,y-1,x-1); pad ring = 0 (conv SAME).
__global__ __launch_bounds__(256) void pad_kernel(
    const float* __restrict__ img, unsigned short* __restrict__ pad)
{
    int i = blockIdx.x * 256 + threadIdx.x;      // cell within one sample
    if (i >= 66 * 66 * 66) return;
    int b = blockIdx.y;
    int z = i / 4356;
    int rem = i - z * 4356;
    int y = rem / 66;
    int x = rem - y * 66;
    float v = 0.f;
    if (z >= 1 && z <= 64 && y >= 1 && y <= 64 && x >= 1 && x <= 64)
        v = img[((size_t)b << 19) + ((z - 1) << 12) + ((y - 1) << 6) + (x - 1)];
    pad[(size_t)b * 287496 + i] = (unsigned short)f2bf(v);
}

// ============ gate via MFMA: 512-thread blocks (8 waves) =====================
// Same math as the round-4 frozen gate; only block shape changes. 2048 blocks
// x 8 waves: __launch_bounds__(512,8) (VGPR cap 64 >= our 52) permits
// 4 blocks/CU = 32 waves/CU; B-build amortizes over 8 waves. Tests whether the
// ~16us of gate issue-bubbles are block-dispatch-granularity bound.
__global__ __launch_bounds__(512, 8) void gate_mfma(
    const unsigned short* __restrict__ pad,
    const float* __restrict__ hw, const float* __restrict__ hb,
    const float* __restrict__ pw, float* __restrict__ p)
{
    __shared__ int4 Bsh[10 * 64];        // [t][lane] 16B fragments

    const int lane = threadIdx.x & 63;
    const int col  = lane & 15;          // B: channel-in-tile; A: voxel m
    const int q    = lane >> 4;
    const int wid  = threadIdx.x >> 6;   // 0..7
    const int W    = blockIdx.x * 8 + wid;   // 16384 waves; row = W

    // ---- build B tiles cooperatively: wave w builds t = w, w+8
    for (int t = wid; t < 10; t += 8) {
        int c = 16 * t + col;
        bool cv = c < 150;
        unsigned hv[8];
        #pragma unroll
        for (int j = 0; j < 8; ++j) {
            int k = 8 * q + j;
            float wv = 0.f;
            if (cv) {
                if (k < 27) wv = hw[c * 27 + k];
                else if (k == 27) wv = hb[c];
            }
            hv[j] = f2bf(wv);
        }
        Bsh[t * 64 + lane] = make_int4(hv[0] | (hv[1] << 16), hv[2] | (hv[3] << 16),
                                       hv[4] | (hv[5] << 16), hv[6] | (hv[7] << 16));
    }
    // ---- pw per lane (L1-resident after first wave)
    float pwv[10];
    #pragma unroll
    for (int t = 0; t < 10; ++t) {
        int c = 16 * t + col;
        pwv[t] = (c < 150) ? pw[c] : 0.f;
    }
    __syncthreads();

    int4 bfrag[10];
    #pragma unroll
    for (int t = 0; t < 10; ++t) bfrag[t] = Bsh[t * 64 + lane];

    // ---- per-lane A-tap offsets into padded volume (loop-invariant)
    int offL[8]; unsigned cstA[8]; bool ldA[8];
    #pragma unroll
    for (int j = 0; j < 8; ++j) {
        int k = 8 * q + j;
        int dz = (k * 57) >> 9;          // k/9 for k<32
        int rem = k - 9 * dz;
        int dy = (rem * 171) >> 9;       // rem/3
        int dx = rem - 3 * dy;
        ldA[j]  = (k < 27);
        offL[j] = (k < 27) ? (dz * 4356 + dy * 66 + dx) : 0;
        cstA[j] = (k == 27) ? 0x3F80u : 0u;   // bias row: bf16(1.0)
    }

    // ---- 4 groups of 16 voxels per wave: one full x-row (y=W&63)
    int y = W & 63, zz = (W >> 6) & 63, b = W >> 12;
    int rbase = b * 287496 + zz * 4356 + y * 66 + col;

    #pragma unroll 2
    for (int i = 0; i < 4; ++i) {
        int x0    = i << 4;
        int abase = rbase + x0;

        unsigned av[8];
        #pragma unroll
        for (int j = 0; j < 8; ++j) {
            unsigned v = pad[abase + offL[j]];
            av[j] = ldA[j] ? v : cstA[j];
        }
        union { int4 i4; short8 s8; } af, bfu;
        af.i4 = make_int4(av[0] | (av[1] << 16), av[2] | (av[3] << 16),
                          av[4] | (av[5] << 16), av[6] | (av[7] << 16));

        const f32x4 zero = {0.f, 0.f, 0.f, 0.f};
        f32x4 rr[10];
        #pragma unroll
        for (int t = 0; t < 10; ++t) {
            bfu.i4 = bfrag[t];
            rr[t] = __builtin_amdgcn_mfma_f32_16x16x32_bf16(af.s8, bfu.s8, zero, 0, 0, 0);
        }
        float ax = 0.f, ay = 0.f, az = 0.f, aw = 0.f;
        #pragma unroll
        for (int t = 0; t < 10; ++t) {
            ax = fmaf(pwv[t], fmaxf(rr[t].x, 0.f), ax);
            ay = fmaf(pwv[t], fmaxf(rr[t].y, 0.f), ay);
            az = fmaf(pwv[t], fmaxf(rr[t].z, 0.f), az);
            aw = fmaf(pwv[t], fmaxf(rr[t].w, 0.f), aw);
        }
        // sum across the 16 cols: DPP prefix-scan (shr 1,2,4,8); col 15 = total
        ax += dpp_shr1(ax); ax += dpp_shr2(ax); ax += dpp_shr4(ax); ax += dpp_shr8(ax);
        ay += dpp_shr1(ay); ay += dpp_shr2(ay); ay += dpp_shr4(ay); ay += dpp_shr8(ay);
        az += dpp_shr1(az); az += dpp_shr2(az); az += dpp_shr4(az); az += dpp_shr8(az);
        aw += dpp_shr1(aw); aw += dpp_shr2(aw); aw += dpp_shr4(aw); aw += dpp_shr8(aw);
        if (col == 15) {                 // rows 4q..4q+3 = x0+4q..x0+4q+3
            float4 o;
            o.x = 1.f / (1.f + __expf(-ax));
            o.y = 1.f / (1.f + __expf(-ay));
            o.z = 1.f / (1.f + __expf(-az));
            o.w = 1.f / (1.f + __expf(-aw));
            *(float4*)(p + (b << 18) + (zz << 12) + (y << 6) + x0 + 4 * q) = o;
        }
    }
}

// ============ fused propagation v4 TEMPLATE (unchanged from round 14) =========
// Margin m = T; cube (2T+4)z x (2T+8)y x 64x; output 4z x 8y x 64x; threads
// 2 x 16 x YC. Halves own HF = T+2 planes in registers, MIRRORED. Separable
// 3^3 max: z in regs, x via DPP, y via LDS t-planes. VEX boundary exchange.
// XCD-chunk swizzle. Plan: 6 x T4 + 2 x T3 = 30 iterations (model optimum).
template<int T>
__global__ __launch_bounds__(512, 4) void prop_kernel(
    const float* __restrict__ vin, int sstride,
    const float* __restrict__ rimg,   // r base = img + 2^18, sample stride 2^19
    const float* __restrict__ pbuf,   // p, sample stride 2^18
    float* __restrict__ vout)
{
    constexpr int YC = 8 + 2 * T;     // rows in tile
    constexpr int PL = 64 * YC;       // floats per plane
    constexpr int P  = 2 * T + 4;     // z planes in cube
    constexpr int HF = T + 2;         // planes per half
    __shared__ float TL[(P - 2) * PL];   // t planes, slot = z-1 (z in [1,P-1))
    __shared__ float VEX[2 * PL];        // slot h: half h's plane HF-1+h

    int hwb = blockIdx.x;             // hw id round-robins XCDs
    int blk = (hwb & 7) * 64 + (hwb >> 3);   // bijective XCD-chunk swizzle
    int b  = blk >> 7;                // logical: b(4) x tz(16) x ty(8)
    int tz = ((blk >> 3) & 15) << 2;
    int ty = (blk & 7) << 3;

    const float* vb = vin  + (size_t)b * sstride;
    const float* rb = rimg + ((size_t)b << 19);
    const float* pb = pbuf + ((size_t)b << 18);
    float*       ob = vout + ((size_t)b << 18);

    int tid  = threadIdx.x;
    int h    = (tid >= 16 * YC);      // z-half (16-lane rows stay (y,h)-uniform)
    int t2   = tid - h * 16 * YC;
    int x4   = t2 & 15, x0 = x4 << 2;
    int yy   = t2 >> 4;               // 0..YC-1

    int gy = ty + yy - T;
    bool vy = (unsigned)gy < 64u;
    int lbase = yy * 64 + x0;
    int goff  = gy * 64 + x0;

    // ---- load own half-column into registers (mirrored for h1)
    float4 v[HF];
    #pragma unroll
    for (int zi = 0; zi < HF; ++zi) {
        int z  = h ? (P - 1 - zi) : zi;
        int gz = tz + z - T;
        float4 val = make_float4(NEG_INF, NEG_INF, NEG_INF, NEG_INF);
        if (vy && ((unsigned)gz < 64u)) val = *(const float4*)(vb + (gz << 12) + goff);
        v[zi] = val;
    }
    // boundary plane exchange: each half exposes zi=HF-1 (planes HF-1, HF)
    *(float4*)(VEX + h * PL + lbase) = v[HF - 1];
    __syncthreads();

    #pragma unroll
    for (int it = 0; it < T; ++it) {
        const int lo = 1 + it;                   // active zi in [lo,HF)
        bool act_t = (yy >= lo - 1) && (yy < YC - lo + 1);
        bool act   = (yy >= lo) && (yy < YC - lo);

        // ---- phase A: z-max (regs) -> x-window (DPP) -> write t planes
        float4 vexN = *(const float4*)(VEX + (h ^ 1) * PL + lbase);
        float4 t[T + 1];
        #pragma unroll
        for (int zi = lo; zi < HF; ++zi) {
            float4 za = v[zi - 1];
            float4 zb = v[zi];
            float4 zc = (zi == HF - 1) ? vexN : v[zi + 1];
            float4 zm;
            zm.x = fmaxf(fmaxf(za.x, zb.x), zc.x);
            zm.y = fmaxf(fmaxf(za.y, zb.y), zc.y);
            zm.z = fmaxf(fmaxf(za.z, zb.z), zc.z);
            zm.w = fmaxf(fmaxf(za.w, zb.w), zc.w);
            float lm = dpp_shr1(zm.w);           // lane i-1's zm.w
            float rm = dpp_shl1(zm.x);           // lane i+1's zm.x
            if (x4 == 0)  lm = NEG_INF;
            if (x4 == 15) rm = NEG_INF;
            float4 tt;
            tt.x = fmaxf(lm, fmaxf(zm.x, zm.y));
            tt.y = fmaxf(zm.x, fmaxf(zm.y, zm.z));
            tt.z = fmaxf(zm.y, fmaxf(zm.z, zm.w));
            tt.w = fmaxf(fmaxf(zm.z, zm.w), rm);
            t[zi - lo] = tt;
            int z = h ? (P - 1 - zi) : zi;       // slot z-1 (single writer)
            if (act_t) *(float4*)(TL + (z - 1) * PL + lbase) = tt;
        }
        __syncthreads();

        // ---- phase C: y-combine from LDS, update v in registers
        #pragma unroll
        for (int zi = lo; zi < HF; ++zi) {
            int z  = h ? (P - 1 - zi) : zi;
            int gz = tz + z - T;
            if (act) {
                const float* tp = TL + (z - 1) * PL + lbase;
                float4 tu = *(const float4*)(tp - 64);
                float4 td = *(const float4*)(tp + 64);
                float4 ts = t[zi - lo];
                float4 m3;
                m3.x = fmaxf(fmaxf(tu.x, td.x), ts.x);
                m3.y = fmaxf(fmaxf(tu.y, td.y), ts.y);
                m3.z = fmaxf(fmaxf(tu.z, td.z), ts.z);
                m3.w = fmaxf(fmaxf(tu.w, td.w), ts.w);
                if (vy && ((unsigned)gz < 64u)) {
                    int off = (gz << 12) + goff;
                    float4 pv = *(const float4*)(pb + off);
                    float4 rv = *(const float4*)(rb + off);
                    float4 nv;
                    nv.x = fmaxf(v[zi].x, fmaf(pv.x, m3.x - rv.x, rv.x));
                    nv.y = fmaxf(v[zi].y, fmaf(pv.y, m3.y - rv.y, rv.y));
                    nv.z = fmaxf(v[zi].z, fmaf(pv.z, m3.z - rv.z, rv.z));
                    nv.w = fmaxf(v[zi].w, fmaf(pv.w, m3.w - rv.w, rv.w));
                    v[zi] = nv;
                    if (it == T - 1) *(float4*)(ob + off) = nv;
                }
            }
        }
        // refresh boundary plane with this iteration's value
        *(float4*)(VEX + h * PL + lbase) = v[HF - 1];
        __syncthreads();
    }
}

extern "C" void kernel_launch(void* const* d_in, const int* in_sizes, int n_in,
                              void* d_out, int out_size, void* d_ws, size_t ws_size,
                              hipStream_t stream) {
    const float* img = (const float*)d_in[0];   // (4,2,64,64,64)
    const float* hw  = (const float*)d_in[1];   // (150,27)
    const float* hb  = (const float*)d_in[2];   // (150,)
    const float* pw  = (const float*)d_in[3];   // (150,)
    // d_in[4] = k (device scalar); reference fixes k=30.

    float* out = (float*)d_out;                      // X buffer (4 MB)
    float* p   = (float*)d_ws;                       // 4 MB
    float* vA  = (float*)((char*)d_ws + (4u << 20)); // Y buffer (4 MB)
    // padded bf16 volume (2.3 MB) shares the vA slot: used only before prop
    unsigned short* pad = (unsigned short*)((char*)d_ws + (4u << 20));

    pad_kernel<<<dim3(1124, 4), 256, 0, stream>>>(img, pad);
    gate_mfma<<<2048, 512, 0, stream>>>(pad, hw, hb, pw, p);

    const float* r0 = img + (1 << 18);  // r channel base, sample stride 2^19

    // 6*T4 + 2*T3 = 30 iterations; ping-pong ends in d_out.
    prop_kernel<4><<<512, 512, 0, stream>>>(r0,  1 << 19, r0, p, vA);   // img -> Y
    prop_kernel<4><<<512, 512, 0, stream>>>(vA,  1 << 18, r0, p, out);  // Y -> X
    prop_kernel<4><<<512, 512, 0, stream>>>(out, 1 << 18, r0, p, vA);
    prop_kernel<4><<<512, 512, 0, stream>>>(vA,  1 << 18, r0, p, out);
    prop_kernel<4><<<512, 512, 0, stream>>>(out, 1 << 18, r0, p, vA);
    prop_kernel<4><<<512, 512, 0, stream>>>(vA,  1 << 18, r0, p, out);
    prop_kernel<3><<<512, 448, 0, stream>>>(out, 1 << 18, r0, p, vA);
    prop_kernel<3><<<512, 448, 0, stream>>>(vA,  1 << 18, r0, p, out);  // -> d_out
}

// Round 16
// 172.789 us; speedup vs baseline: 1.5765x; 1.5765x over previous
//
#include <hip/hip_runtime.h>
#include <math.h>

#define NEG_INF (-__builtin_inff())

typedef __attribute__((ext_vector_type(8))) short short8;
typedef __attribute__((ext_vector_type(4))) float f32x4;

__device__ __forceinline__ unsigned f2bf(float f) {   // fp32 -> bf16 bits (RNE)
    union { float f; unsigned u; } v; v.f = f;
    return (v.u + 0x7fffu + ((v.u >> 16) & 1u)) >> 16;
}

// DPP row shifts within 16-lane rows. row_shr:n (0x110|n): lane i reads lane
// i-n within its 16-lane row; bound_ctrl=true -> out-of-row reads 0.
__device__ __forceinline__ float dpp_shr1(float x) {
    return __int_as_float(__builtin_amdgcn_update_dpp(
        0, __float_as_int(x), 0x111, 0xF, 0xF, true));
}
__device__ __forceinline__ float dpp_shr2(float x) {
    return __int_as_float(__builtin_amdgcn_update_dpp(
        0, __float_as_int(x), 0x112, 0xF, 0xF, true));
}
__device__ __forceinline__ float dpp_shr4(float x) {
    return __int_as_float(__builtin_amdgcn_update_dpp(
        0, __float_as_int(x), 0x114, 0xF, 0xF, true));
}
__device__ __forceinline__ float dpp_shr8(float x) {
    return __int_as_float(__builtin_amdgcn_update_dpp(
        0, __float_as_int(x), 0x118, 0xF, 0xF, true));
}
__device__ __forceinline__ float dpp_shl1(float x) {
    return __int_as_float(__builtin_amdgcn_update_dpp(
        0, __float_as_int(x), 0x101, 0xF, 0xF, true));
}

// ============ pad kernel: x channel -> zero-padded (4,66,66,66) bf16 ============
// Padded cell (z,y,x) = volume voxel (z-1,y-1,x-1); pad ring = 0 (conv SAME).
__global__ __launch_bounds__(256) void pad_kernel(
    const float* __restrict__ img, unsigned short* __restrict__ pad)
{
    int i = blockIdx.x * 256 + threadIdx.x;      // cell within one sample
    if (i >= 66 * 66 * 66) return;
    int b = blockIdx.y;
    int z = i / 4356;
    int rem = i - z * 4356;
    int y = rem / 66;
    int x = rem - y * 66;
    float v = 0.f;
    if (z >= 1 && z <= 64 && y >= 1 && y <= 64 && x >= 1 && x <= 64)
        v = img[((size_t)b << 19) + ((z - 1) << 12) + ((y - 1) << 6) + (x - 1)];
    pad[(size_t)b * 287496 + i] = (unsigned short)f2bf(v);
}

// ============ gate via MFMA (round-4 frozen: 256 thr, (256,4), VGPR 52) =======
// R15 lesson: (512,8) forced VGPR<=32 -> bfrag/rr spilled to scratch (FETCH
// 2MB->360MB). Gate is VALU-issue bound (~30us of issue per SIMD); this
// structure's floor is ~45us. Do not perturb launch bounds or operand order.
__global__ __launch_bounds__(256, 4) void gate_mfma(
    const unsigned short* __restrict__ pad,
    const float* __restrict__ hw, const float* __restrict__ hb,
    const float* __restrict__ pw, float* __restrict__ p)
{
    __shared__ int4 Bsh[10 * 64];        // [t][lane] 16B fragments

    const int lane = threadIdx.x & 63;
    const int col  = lane & 15;          // B: channel-in-tile; A: voxel m
    const int q    = lane >> 4;
    const int wid  = threadIdx.x >> 6;
    const int W    = blockIdx.x * 4 + wid;   // 16384 waves; row = W

    // ---- build B tiles cooperatively: wave w builds t = w, w+4, w+8
    for (int t = wid; t < 10; t += 4) {
        int c = 16 * t + col;
        bool cv = c < 150;
        unsigned hv[8];
        #pragma unroll
        for (int j = 0; j < 8; ++j) {
            int k = 8 * q + j;
            float wv = 0.f;
            if (cv) {
                if (k < 27) wv = hw[c * 27 + k];
                else if (k == 27) wv = hb[c];
            }
            hv[j] = f2bf(wv);
        }
        Bsh[t * 64 + lane] = make_int4(hv[0] | (hv[1] << 16), hv[2] | (hv[3] << 16),
                                       hv[4] | (hv[5] << 16), hv[6] | (hv[7] << 16));
    }
    // ---- pw per lane (L1-resident after first wave)
    float pwv[10];
    #pragma unroll
    for (int t = 0; t < 10; ++t) {
        int c = 16 * t + col;
        pwv[t] = (c < 150) ? pw[c] : 0.f;
    }
    __syncthreads();

    int4 bfrag[10];
    #pragma unroll
    for (int t = 0; t < 10; ++t) bfrag[t] = Bsh[t * 64 + lane];

    // ---- per-lane A-tap offsets into padded volume (loop-invariant)
    int offL[8]; unsigned cstA[8]; bool ldA[8];
    #pragma unroll
    for (int j = 0; j < 8; ++j) {
        int k = 8 * q + j;
        int dz = (k * 57) >> 9;          // k/9 for k<32
        int rem = k - 9 * dz;
        int dy = (rem * 171) >> 9;       // rem/3
        int dx = rem - 3 * dy;
        ldA[j]  = (k < 27);
        offL[j] = (k < 27) ? (dz * 4356 + dy * 66 + dx) : 0;
        cstA[j] = (k == 27) ? 0x3F80u : 0u;   // bias row: bf16(1.0)
    }

    // ---- 4 groups of 16 voxels per wave: one full x-row (y=W&63)
    int y = W & 63, zz = (W >> 6) & 63, b = W >> 12;
    int rbase = b * 287496 + zz * 4356 + y * 66 + col;

    #pragma unroll 2
    for (int i = 0; i < 4; ++i) {
        int x0    = i << 4;
        int abase = rbase + x0;

        unsigned av[8];
        #pragma unroll
        for (int j = 0; j < 8; ++j) {
            unsigned v = pad[abase + offL[j]];
            av[j] = ldA[j] ? v : cstA[j];
        }
        union { int4 i4; short8 s8; } af, bfu;
        af.i4 = make_int4(av[0] | (av[1] << 16), av[2] | (av[3] << 16),
                          av[4] | (av[5] << 16), av[6] | (av[7] << 16));

        const f32x4 zero = {0.f, 0.f, 0.f, 0.f};
        f32x4 rr[10];
        #pragma unroll
        for (int t = 0; t < 10; ++t) {
            bfu.i4 = bfrag[t];
            rr[t] = __builtin_amdgcn_mfma_f32_16x16x32_bf16(af.s8, bfu.s8, zero, 0, 0, 0);
        }
        float ax = 0.f, ay = 0.f, az = 0.f, aw = 0.f;
        #pragma unroll
        for (int t = 0; t < 10; ++t) {
            ax = fmaf(pwv[t], fmaxf(rr[t].x, 0.f), ax);
            ay = fmaf(pwv[t], fmaxf(rr[t].y, 0.f), ay);
            az = fmaf(pwv[t], fmaxf(rr[t].z, 0.f), az);
            aw = fmaf(pwv[t], fmaxf(rr[t].w, 0.f), aw);
        }
        // sum across the 16 cols: DPP prefix-scan (shr 1,2,4,8); col 15 = total
        ax += dpp_shr1(ax); ax += dpp_shr2(ax); ax += dpp_shr4(ax); ax += dpp_shr8(ax);
        ay += dpp_shr1(ay); ay += dpp_shr2(ay); ay += dpp_shr4(ay); ay += dpp_shr8(ay);
        az += dpp_shr1(az); az += dpp_shr2(az); az += dpp_shr4(az); az += dpp_shr8(az);
        aw += dpp_shr1(aw); aw += dpp_shr2(aw); aw += dpp_shr4(aw); aw += dpp_shr8(aw);
        if (col == 15) {                 // rows 4q..4q+3 = x0+4q..x0+4q+3
            float4 o;
            o.x = 1.f / (1.f + __expf(-ax));
            o.y = 1.f / (1.f + __expf(-ay));
            o.z = 1.f / (1.f + __expf(-az));
            o.w = 1.f / (1.f + __expf(-aw));
            *(float4*)(p + (b << 18) + (zz << 12) + (y << 6) + x0 + 4 * q) = o;
        }
    }
}

// ============ fused propagation v4 TEMPLATE (round-14 state, unchanged) =======
// Margin m = T; cube (2T+4)z x (2T+8)y x 64x; output 4z x 8y x 64x; threads
// 2 x 16 x YC. Halves own HF = T+2 planes in registers, MIRRORED. Separable
// 3^3 max: z in regs, x via DPP, y via LDS t-planes. VEX boundary exchange.
// XCD-chunk swizzle. Plan: 6 x T4 + 2 x T3 = 30 iterations (model optimum).
template<int T>
__global__ __launch_bounds__(512, 4) void prop_kernel(
    const float* __restrict__ vin, int sstride,
    const float* __restrict__ rimg,   // r base = img + 2^18, sample stride 2^19
    const float* __restrict__ pbuf,   // p, sample stride 2^18
    float* __restrict__ vout)
{
    constexpr int YC = 8 + 2 * T;     // rows in tile
    constexpr int PL = 64 * YC;       // floats per plane
    constexpr int P  = 2 * T + 4;     // z planes in cube
    constexpr int HF = T + 2;         // planes per half
    __shared__ float TL[(P - 2) * PL];   // t planes, slot = z-1 (z in [1,P-1))
    __shared__ float VEX[2 * PL];        // slot h: half h's plane HF-1+h

    int hwb = blockIdx.x;             // hw id round-robins XCDs
    int blk = (hwb & 7) * 64 + (hwb >> 3);   // bijective XCD-chunk swizzle
    int b  = blk >> 7;                // logical: b(4) x tz(16) x ty(8)
    int tz = ((blk >> 3) & 15) << 2;
    int ty = (blk & 7) << 3;

    const float* vb = vin  + (size_t)b * sstride;
    const float* rb = rimg + ((size_t)b << 19);
    const float* pb = pbuf + ((size_t)b << 18);
    float*       ob = vout + ((size_t)b << 18);

    int tid  = threadIdx.x;
    int h    = (tid >= 16 * YC);      // z-half (16-lane rows stay (y,h)-uniform)
    int t2   = tid - h * 16 * YC;
    int x4   = t2 & 15, x0 = x4 << 2;
    int yy   = t2 >> 4;               // 0..YC-1

    int gy = ty + yy - T;
    bool vy = (unsigned)gy < 64u;
    int lbase = yy * 64 + x0;
    int goff  = gy * 64 + x0;

    // ---- load own half-column into registers (mirrored for h1)
    float4 v[HF];
    #pragma unroll
    for (int zi = 0; zi < HF; ++zi) {
        int z  = h ? (P - 1 - zi) : zi;
        int gz = tz + z - T;
        float4 val = make_float4(NEG_INF, NEG_INF, NEG_INF, NEG_INF);
        if (vy && ((unsigned)gz < 64u)) val = *(const float4*)(vb + (gz << 12) + goff);
        v[zi] = val;
    }
    // boundary plane exchange: each half exposes zi=HF-1 (planes HF-1, HF)
    *(float4*)(VEX + h * PL + lbase) = v[HF - 1];
    __syncthreads();

    #pragma unroll
    for (int it = 0; it < T; ++it) {
        const int lo = 1 + it;                   // active zi in [lo,HF)
        bool act_t = (yy >= lo - 1) && (yy < YC - lo + 1);
        bool act   = (yy >= lo) && (yy < YC - lo);

        // ---- phase A: z-max (regs) -> x-window (DPP) -> write t planes
        float4 vexN = *(const float4*)(VEX + (h ^ 1) * PL + lbase);
        float4 t[T + 1];
        #pragma unroll
        for (int zi = lo; zi < HF; ++zi) {
            float4 za = v[zi - 1];
            float4 zb = v[zi];
            float4 zc = (zi == HF - 1) ? vexN : v[zi + 1];
            float4 zm;
            zm.x = fmaxf(fmaxf(za.x, zb.x), zc.x);
            zm.y = fmaxf(fmaxf(za.y, zb.y), zc.y);
            zm.z = fmaxf(fmaxf(za.z, zb.z), zc.z);
            zm.w = fmaxf(fmaxf(za.w, zb.w), zc.w);
            float lm = dpp_shr1(zm.w);           // lane i-1's zm.w
            float rm = dpp_shl1(zm.x);           // lane i+1's zm.x
            if (x4 == 0)  lm = NEG_INF;
            if (x4 == 15) rm = NEG_INF;
            float4 tt;
            tt.x = fmaxf(lm, fmaxf(zm.x, zm.y));
            tt.y = fmaxf(zm.x, fmaxf(zm.y, zm.z));
            tt.z = fmaxf(zm.y, fmaxf(zm.z, zm.w));
            tt.w = fmaxf(fmaxf(zm.z, zm.w), rm);
            t[zi - lo] = tt;
            int z = h ? (P - 1 - zi) : zi;       // slot z-1 (single writer)
            if (act_t) *(float4*)(TL + (z - 1) * PL + lbase) = tt;
        }
        __syncthreads();

        // ---- phase C: y-combine from LDS, update v in registers
        #pragma unroll
        for (int zi = lo; zi < HF; ++zi) {
            int z  = h ? (P - 1 - zi) : zi;
            int gz = tz + z - T;
            if (act) {
                const float* tp = TL + (z - 1) * PL + lbase;
                float4 tu = *(const float4*)(tp - 64);
                float4 td = *(const float4*)(tp + 64);
                float4 ts = t[zi - lo];
                float4 m3;
                m3.x = fmaxf(fmaxf(tu.x, td.x), ts.x);
                m3.y = fmaxf(fmaxf(tu.y, td.y), ts.y);
                m3.z = fmaxf(fmaxf(tu.z, td.z), ts.z);
                m3.w = fmaxf(fmaxf(tu.w, td.w), ts.w);
                if (vy && ((unsigned)gz < 64u)) {
                    int off = (gz << 12) + goff;
                    float4 pv = *(const float4*)(pb + off);
                    float4 rv = *(const float4*)(rb + off);
                    float4 nv;
                    nv.x = fmaxf(v[zi].x, fmaf(pv.x, m3.x - rv.x, rv.x));
                    nv.y = fmaxf(v[zi].y, fmaf(pv.y, m3.y - rv.y, rv.y));
                    nv.z = fmaxf(v[zi].z, fmaf(pv.z, m3.z - rv.z, rv.z));
                    nv.w = fmaxf(v[zi].w, fmaf(pv.w, m3.w - rv.w, rv.w));
                    v[zi] = nv;
                    if (it == T - 1) *(float4*)(ob + off) = nv;
                }
            }
        }
        // refresh boundary plane with this iteration's value
        *(float4*)(VEX + h * PL + lbase) = v[HF - 1];
        __syncthreads();
    }
}

extern "C" void kernel_launch(void* const* d_in, const int* in_sizes, int n_in,
                              void* d_out, int out_size, void* d_ws, size_t ws_size,
                              hipStream_t stream) {
    const float* img = (const float*)d_in[0];   // (4,2,64,64,64)
    const float* hw  = (const float*)d_in[1];   // (150,27)
    const float* hb  = (const float*)d_in[2];   // (150,)
    const float* pw  = (const float*)d_in[3];   // (150,)
    // d_in[4] = k (device scalar); reference fixes k=30.

    float* out = (float*)d_out;                      // X buffer (4 MB)
    float* p   = (float*)d_ws;                       // 4 MB
    float* vA  = (float*)((char*)d_ws + (4u << 20)); // Y buffer (4 MB)
    // padded bf16 volume (2.3 MB) shares the vA slot: used only before prop
    unsigned short* pad = (unsigned short*)((char*)d_ws + (4u << 20));

    pad_kernel<<<dim3(1124, 4), 256, 0, stream>>>(img, pad);
    gate_mfma<<<4096, 256, 0, stream>>>(pad, hw, hb, pw, p);

    const float* r0 = img + (1 << 18);  // r channel base, sample stride 2^19

    // 6*T4 + 2*T3 = 30 iterations; ping-pong ends in d_out.
    prop_kernel<4><<<512, 512, 0, stream>>>(r0,  1 << 19, r0, p, vA);   // img -> Y
    prop_kernel<4><<<512, 512, 0, stream>>>(vA,  1 << 18, r0, p, out);  // Y -> X
    prop_kernel<4><<<512, 512, 0, stream>>>(out, 1 << 18, r0, p, vA);
    prop_kernel<4><<<512, 512, 0, stream>>>(vA,  1 << 18, r0, p, out);
    prop_kernel<4><<<512, 512, 0, stream>>>(out, 1 << 18, r0, p, vA);
    prop_kernel<4><<<512, 512, 0, stream>>>(vA,  1 << 18, r0, p, out);
    prop_kernel<3><<<512, 448, 0, stream>>>(out, 1 << 18, r0, p, vA);
    prop_kernel<3><<<512, 448, 0, stream>>>(vA,  1 << 18, r0, p, out);  // -> d_out
}